// Round 5
// baseline (212.412 us; speedup 1.0000x reference)
//
#include <hip/hip_runtime.h>
#include <math.h>

#define DD 128   // feature dim, fixed by the reference

// Per-element update: z = x*a + c; z2 = z*z; p *= (1 - z2); s += z2.
#define UPD4(P, S, XV)                                                          \
    {                                                                           \
        float z, z2;                                                            \
        z = fmaf((XV).x, av.x, cv.x); z2 = z * z; P = fmaf(-z2, P, P); S += z2; \
        z = fmaf((XV).y, av.y, cv.y); z2 = z * z; P = fmaf(-z2, P, P); S += z2; \
        z = fmaf((XV).z, av.z, cv.z); z2 = z * z; P = fmaf(-z2, P, P); S += z2; \
        z = fmaf((XV).w, av.w, cv.w); z2 = z * z; P = fmaf(-z2, P, P); S += z2; \
    }

// ======================= real kernel: exact R1 (21.2 us) =======================
__global__ __launch_bounds__(512, 4)
void wavelet_prod_kernel(const float* __restrict__ x,
                         const float* __restrict__ bias,
                         const float* __restrict__ scale,
                         float* __restrict__ out,
                         int B, int N)
{
    __shared__ float4 a_s[64 * 32];
    __shared__ float4 c_s[64 * 32];

    const int tid  = threadIdx.x;
    const int lane = tid & 63;
    const int wave = tid >> 6;

    const int n0 = blockIdx.x * 64;
    const int bb = blockIdx.y * 32;

    {
        const float4* b4 = (const float4*)(bias  + (size_t)n0 * DD);
        const float4* s4 = (const float4*)(scale + (size_t)n0 * DD);
        #pragma unroll
        for (int k = 0; k < 4; ++k) {
            int flat = tid + k * 512;
            int r = flat >> 5;
            int q = flat & 31;
            float4 sv = s4[flat];
            float4 bv = b4[flat];
            float4 av, cv;
            av.x = 1.0f / sv.x; av.y = 1.0f / sv.y;
            av.z = 1.0f / sv.z; av.w = 1.0f / sv.w;
            cv.x = -bv.x * av.x; cv.y = -bv.y * av.y;
            cv.z = -bv.z * av.z; cv.w = -bv.w * av.w;
            int dst = r * 32 + (q ^ (r & 7));
            a_s[dst] = av;
            c_s[dst] = cv;
        }
    }
    __syncthreads();

    const int b0 = __builtin_amdgcn_readfirstlane(bb + wave * 4);
    const float4* xr = (const float4*)(x + (size_t)b0 * DD);

    const float4* arow = a_s + lane * 32;
    const float4* crow = c_s + lane * 32;
    const int sw = lane & 7;

    float p0 = 1.f, p1 = 1.f, p2 = 1.f, p3 = 1.f;
    float s0 = 0.f, s1 = 0.f, s2 = 0.f, s3 = 0.f;

    const float kexp = -0.7213475204444817f;

    #pragma unroll
    for (int f = 0; f < 8; ++f) {
        #pragma unroll
        for (int cc = 0; cc < 4; ++cc) {
            const int q    = f * 4 + cc;
            const int slot = q ^ sw;
            float4 av = arow[slot];
            float4 cv = crow[slot];
            float4 x0 = xr[q];
            float4 x1 = xr[32 + q];
            float4 x2 = xr[64 + q];
            float4 x3 = xr[96 + q];
            UPD4(p0, s0, x0);
            UPD4(p1, s1, x1);
            UPD4(p2, s2, x2);
            UPD4(p3, s3, x3);
        }
        p0 *= exp2f(s0 * kexp); s0 = 0.f;
        p1 *= exp2f(s1 * kexp); s1 = 0.f;
        p2 *= exp2f(s2 * kexp); s2 = 0.f;
        p3 *= exp2f(s3 * kexp); s3 = 0.f;
    }

    float* o = out + (size_t)b0 * N + n0 + lane;
    o[0 * N] = p0;
    o[1 * N] = p1;
    o[2 * N] = p2;
    o[3 * N] = p3;
}

// ======================= diagnostic kernels (write to d_ws) =======================
// MODE 0: full work x REPS                  -> per-iteration baseline
// MODE 1: no global x loads in the loop     -> isolates vmem cost
// MODE 2: no LDS a/c reads in the loop      -> isolates ds_read cost
// MODE 3: folds without exp2f               -> isolates libm transcendental cost
#define REPS 4

template<int MODE>
__global__ __launch_bounds__(512, 4)
void diag_kernel(const float* __restrict__ x,
                 const float* __restrict__ bias,
                 const float* __restrict__ scale,
                 float* __restrict__ out,
                 int B, int N)
{
    __shared__ float4 a_s[64 * 32];
    __shared__ float4 c_s[64 * 32];

    const int tid  = threadIdx.x;
    const int lane = tid & 63;
    const int wave = tid >> 6;

    const int n0 = blockIdx.x * 64;
    const int bb = blockIdx.y * 32;

    {
        const float4* b4 = (const float4*)(bias  + (size_t)n0 * DD);
        const float4* s4 = (const float4*)(scale + (size_t)n0 * DD);
        #pragma unroll
        for (int k = 0; k < 4; ++k) {
            int flat = tid + k * 512;
            int r = flat >> 5;
            int q = flat & 31;
            float4 sv = s4[flat];
            float4 bv = b4[flat];
            float4 av, cv;
            av.x = 1.0f / sv.x; av.y = 1.0f / sv.y;
            av.z = 1.0f / sv.z; av.w = 1.0f / sv.w;
            cv.x = -bv.x * av.x; cv.y = -bv.y * av.y;
            cv.z = -bv.z * av.z; cv.w = -bv.w * av.w;
            int dst = r * 32 + (q ^ (r & 7));
            a_s[dst] = av;
            c_s[dst] = cv;
        }
    }
    __syncthreads();

    const int b0 = __builtin_amdgcn_readfirstlane(bb + wave * 4);
    const float4* xr = (const float4*)(x + (size_t)b0 * DD);

    const float4* arow = a_s + lane * 32;
    const float4* crow = c_s + lane * 32;
    const int sw = lane & 7;

    float p0 = 1.f, p1 = 1.f, p2 = 1.f, p3 = 1.f;
    float s0 = 0.f, s1 = 0.f, s2 = 0.f, s3 = 0.f;

    const float kexp = -0.7213475204444817f;

    // Preloads for the ablated modes (kept live through use in the loop).
    float4 xp0 = xr[0], xp1 = xr[32], xp2 = xr[64], xp3 = xr[96];  // MODE 1
    float4 avP = arow[sw], cvP = crow[sw];                          // MODE 2

    #pragma unroll 1
    for (int rep = 0; rep < REPS; ++rep) {
        #pragma unroll
        for (int f = 0; f < 8; ++f) {
            #pragma unroll
            for (int cc = 0; cc < 4; ++cc) {
                const int q = f * 4 + cc;
                float4 av, cv, x0, x1, x2, x3;
                if (MODE == 2) { av = avP; cv = cvP; }
                else {
                    // rep-dependent slot defeats LICM; XOR keeps the
                    // conflict-free permutation within each 8-lane group.
                    const int slot = (q ^ sw) ^ (rep & 7);
                    av = arow[slot];
                    cv = crow[slot];
                }
                if (MODE == 1) { x0 = xp0; x1 = xp1; x2 = xp2; x3 = xp3; }
                else {
                    const int qi = (q + rep) & 31;   // rep-dependent, defeats LICM
                    x0 = xr[qi];
                    x1 = xr[32 + qi];
                    x2 = xr[64 + qi];
                    x3 = xr[96 + qi];
                }
                UPD4(p0, s0, x0);
                UPD4(p1, s1, x1);
                UPD4(p2, s2, x2);
                UPD4(p3, s3, x3);
            }
            if (MODE == 3) {
                p0 *= 0.9999f + s0 * 1e-8f; s0 = 0.f;   // keep s live, no exp
                p1 *= 0.9999f + s1 * 1e-8f; s1 = 0.f;
                p2 *= 0.9999f + s2 * 1e-8f; s2 = 0.f;
                p3 *= 0.9999f + s3 * 1e-8f; s3 = 0.f;
            } else {
                p0 *= exp2f(s0 * kexp); s0 = 0.f;
                p1 *= exp2f(s1 * kexp); s1 = 0.f;
                p2 *= exp2f(s2 * kexp); s2 = 0.f;
                p3 *= exp2f(s3 * kexp); s3 = 0.f;
            }
        }
    }

    float* o = out + (size_t)b0 * N + n0 + lane;
    o[0 * N] = p0;
    o[1 * N] = p1;
    o[2 * N] = p2;
    o[3 * N] = p3;
}

extern "C" void kernel_launch(void* const* d_in, const int* in_sizes, int n_in,
                              void* d_out, int out_size, void* d_ws, size_t ws_size,
                              hipStream_t stream)
{
    const float* x     = (const float*)d_in[0];
    const float* bias  = (const float*)d_in[1];
    const float* scale = (const float*)d_in[2];
    float* out = (float*)d_out;

    const int B = in_sizes[0] / DD;   // 2048
    const int N = in_sizes[1] / DD;   // 512

    dim3 grid(N / 64, B / 32);        // (8, 64) = 512 blocks
    wavelet_prod_kernel<<<grid, 512, 0, stream>>>(x, bias, scale, out, B, N);

    // Diagnostic ablation kernels -> workspace (deterministic; results unused).
    if (ws_size >= 4 * (size_t)out_size * sizeof(float)) {
        float* w = (float*)d_ws;
        diag_kernel<0><<<grid, 512, 0, stream>>>(x, bias, scale, w + 0 * (size_t)out_size, B, N);
        diag_kernel<1><<<grid, 512, 0, stream>>>(x, bias, scale, w + 1 * (size_t)out_size, B, N);
        diag_kernel<2><<<grid, 512, 0, stream>>>(x, bias, scale, w + 2 * (size_t)out_size, B, N);
        diag_kernel<3><<<grid, 512, 0, stream>>>(x, bias, scale, w + 3 * (size_t)out_size, B, N);
    }
}